// Round 2
// baseline (127.312 us; speedup 1.0000x reference)
//
#include <hip/hip_runtime.h>
#include <math.h>

#define BATCH   64
#define SEQ     8192
#define NHEAD   8
#define HIDDEN  256
#define TCHUNK  64
#define CHUNKS  128                     // SEQ / TCHUNK
#define BT      16                      // batches per block
#define BGROUPS 4                       // BATCH / BT
#define SCALE   0.17677669529663687f    // 1/sqrt(32)

// ws layout (floats):
#define WS_ALPHA 0
#define WS_M     512
#define WS_RZ    1024
#define WS_ACC   1536                   // 64*256 accumulators (zeroed by stats)

#define CPAD 20                         // head stride in coeff row (bank-conflict-free)
#define CROW (NHEAD * CPAD)             // 160 floats per t-row
#define XPAD 65

// ---------------------------------------------------------------- kernel 1
// Per batch b: zero acc region; compute head constants A_h,C_h; alpha[b,h];
// m[b,h] = max(alpha*xmax, alpha*xmin); Z via one pass over x (8 heads at once).
__global__ void stats_kernel(const float* __restrict__ x,
                             const float* __restrict__ qw,
                             const float* __restrict__ qb,
                             const float* __restrict__ kw,
                             float* __restrict__ ws) {
    __shared__ float sA[NHEAD], sC[NHEAD];
    __shared__ float smx[4], smn[4], szz[32];
    int b   = blockIdx.x;
    int tid = threadIdx.x;
    int w   = tid >> 6;
    int lane = tid & 63;

    // zero the global accumulator slice for this batch
    ws[WS_ACC + b * HIDDEN + tid] = 0.f;

    // head constants: A_h = sum qw*kw, C_h = sum qb*kw over 16 dims
    if (tid < 128) {
        float p1 = qw[tid] * kw[tid];
        float p2 = qb[tid] * kw[tid];
        #pragma unroll
        for (int msk = 1; msk < 16; msk <<= 1) {
            p1 += __shfl_xor(p1, msk);
            p2 += __shfl_xor(p2, msk);
        }
        if ((tid & 15) == 0) { sA[tid >> 4] = p1; sC[tid >> 4] = p2; }
    }

    // load x into registers (coalesced), local min/max
    const float* xb = x + (size_t)b * SEQ;
    float xr[32];
    float mx = -INFINITY, mn = INFINITY;
    #pragma unroll
    for (int i = 0; i < 32; ++i) {
        xr[i] = xb[tid + i * 256];
        mx = fmaxf(mx, xr[i]);
        mn = fminf(mn, xr[i]);
    }
    #pragma unroll
    for (int msk = 32; msk >= 1; msk >>= 1) {
        mx = fmaxf(mx, __shfl_xor(mx, msk));
        mn = fminf(mn, __shfl_xor(mn, msk));
    }
    if (lane == 0) { smx[w] = mx; smn[w] = mn; }
    __syncthreads();   // sA/sC + smx/smn ready

    float xmax = fmaxf(fmaxf(smx[0], smx[1]), fmaxf(smx[2], smx[3]));
    float xmin = fminf(fminf(smn[0], smn[1]), fminf(smn[2], smn[3]));
    float x0 = xb[0];

    float al[NHEAD], mh[NHEAD], ls[NHEAD];
    #pragma unroll
    for (int h = 0; h < NHEAD; ++h) {
        al[h] = SCALE * (x0 * sA[h] + sC[h]);
        mh[h] = fmaxf(al[h] * xmax, al[h] * xmin);   // = max_t alpha*x_t
        ls[h] = 0.f;
    }
    #pragma unroll 4
    for (int i = 0; i < 32; ++i) {
        float e = xr[i];
        #pragma unroll
        for (int h = 0; h < NHEAD; ++h)
            ls[h] += __expf(al[h] * e - mh[h]);
    }
    #pragma unroll
    for (int h = 0; h < NHEAD; ++h) {
        float v = ls[h];
        #pragma unroll
        for (int msk = 32; msk >= 1; msk >>= 1)
            v += __shfl_xor(v, msk);
        if (lane == 0) szz[w * NHEAD + h] = v;
    }
    __syncthreads();
    if (tid < NHEAD) {
        float Z = szz[tid] + szz[8 + tid] + szz[16 + tid] + szz[24 + tid];
        ws[WS_ALPHA + b * NHEAD + tid] = al[tid];
        ws[WS_M     + b * NHEAD + tid] = mh[tid];
        ws[WS_RZ    + b * NHEAD + tid] = 1.f / Z;
    }
}

// ---------------------------------------------------------------- kernel 2
// Context contraction with 16-batch reuse of each G element.
// grid (CHUNKS, BGROUPS), 256 threads. Wave w handles t in [w*16, w*16+16),
// each lane owns 4 columns; 16 float accumulators (one per batch).
__global__ void contract_kernel(const float* __restrict__ x,
                                const float* __restrict__ G,
                                float* __restrict__ ws) {
    __shared__ float coeff[TCHUNK * CROW];     // 40 KB, padded layout
    __shared__ float xs[BT * XPAD];            // 4.2 KB
    __shared__ float sal[BT * NHEAD], smm[BT * NHEAD], srz[BT * NHEAD];

    int chunk = blockIdx.x;            // 0..127
    int bg    = blockIdx.y;            // 0..3
    int b0    = bg * BT;
    int tid   = threadIdx.x;
    int w     = tid >> 6;
    int lane  = tid & 63;
    int t0    = chunk * TCHUNK;

    if (tid < BT * NHEAD) {            // params [bi][h]
        int bi = tid >> 3, hh = tid & 7;
        int g = (b0 + bi) * NHEAD + hh;
        sal[tid] = ws[WS_ALPHA + g];
        smm[tid] = ws[WS_M + g];
        srz[tid] = ws[WS_RZ + g];
    }
    // stage x[b0..b0+16)[t0..t0+64) -> xs (padded)
    for (int i = tid; i < BT * TCHUNK; i += 256) {
        int bi = i >> 6, t = i & 63;
        xs[bi * XPAD + t] = x[(size_t)(b0 + bi) * SEQ + t0 + t];
    }
    __syncthreads();

    // coeff[t][h][bi] = exp(a*x - m) * rz * x ; fixed (bi,h) per thread
    {
        int bi = tid & 15;
        int hh = (tid >> 4) & 7;
        int p  = bi * NHEAD + hh;
        float a  = sal[p], mm = smm[p], rz = srz[p];
        int tb = tid >> 7;             // t parity
        #pragma unroll 8
        for (int j = 0; j < 32; ++j) {
            int t = tb + j * 2;
            float e = xs[bi * XPAD + t];
            coeff[t * CROW + hh * CPAD + bi] = __expf(a * e - mm) * rz * e;
        }
    }
    __syncthreads();

    int h = lane >> 3;                 // head of this lane's 4 columns
    const float* gp = G + (size_t)(t0 + w * 16) * HIDDEN + lane * 4;
    float4 g = *(const float4*)gp;
    float4 acc[BT];
    #pragma unroll
    for (int bi = 0; bi < BT; ++bi) acc[bi] = make_float4(0.f, 0.f, 0.f, 0.f);

    #pragma unroll 2
    for (int t = 0; t < 16; ++t) {
        int tn = (t + 1 < 16) ? t + 1 : 15;
        float4 gn = *(const float4*)(gp + (size_t)tn * HIDDEN);   // prefetch
        const float* cr = coeff + (w * 16 + t) * CROW + h * CPAD;
        float4 c0 = *(const float4*)(cr);
        float4 c1 = *(const float4*)(cr + 4);
        float4 c2 = *(const float4*)(cr + 8);
        float4 c3 = *(const float4*)(cr + 12);
        float cc[BT] = {c0.x, c0.y, c0.z, c0.w, c1.x, c1.y, c1.z, c1.w,
                        c2.x, c2.y, c2.z, c2.w, c3.x, c3.y, c3.z, c3.w};
        #pragma unroll
        for (int bi = 0; bi < BT; ++bi) {
            acc[bi].x = fmaf(cc[bi], g.x, acc[bi].x);
            acc[bi].y = fmaf(cc[bi], g.y, acc[bi].y);
            acc[bi].z = fmaf(cc[bi], g.z, acc[bi].z);
            acc[bi].w = fmaf(cc[bi], g.w, acc[bi].w);
        }
        g = gn;
    }

    // cross-wave reduction in LDS (reuse coeff region), then wave-0 atomics
    __syncthreads();
    float* red = coeff;                // needs 2*BT*HIDDEN = 8192 floats <= 10240
    if (w >= 2) {
        float* r = red + (size_t)(w - 2) * BT * HIDDEN;
        #pragma unroll
        for (int bi = 0; bi < BT; ++bi)
            *(float4*)(r + bi * HIDDEN + lane * 4) = acc[bi];
    }
    __syncthreads();
    if (w < 2) {
        const float* r = red + (size_t)w * BT * HIDDEN;
        #pragma unroll
        for (int bi = 0; bi < BT; ++bi) {
            float4 v = *(const float4*)(r + bi * HIDDEN + lane * 4);
            acc[bi].x += v.x; acc[bi].y += v.y; acc[bi].z += v.z; acc[bi].w += v.w;
        }
    }
    __syncthreads();
    if (w == 1) {
        #pragma unroll
        for (int bi = 0; bi < BT; ++bi)
            *(float4*)(red + bi * HIDDEN + lane * 4) = acc[bi];
    }
    __syncthreads();
    if (w == 0) {
        #pragma unroll
        for (int bi = 0; bi < BT; ++bi) {
            float4 v = *(const float4*)(red + bi * HIDDEN + lane * 4);
            float* dst = ws + WS_ACC + (size_t)(b0 + bi) * HIDDEN + lane * 4;
            atomicAdd(dst + 0, acc[bi].x + v.x);
            atomicAdd(dst + 1, acc[bi].y + v.y);
            atomicAdd(dst + 2, acc[bi].z + v.z);
            atomicAdd(dst + 3, acc[bi].w + v.w);
        }
    }
}

// ---------------------------------------------------------------- kernel 3
// Load acc, 256-element descending bitonic sort per batch.
__global__ void reduce_sort_kernel(const float* __restrict__ ws,
                                   float* __restrict__ out) {
    __shared__ float v[HIDDEN];
    int b   = blockIdx.x;
    int tid = threadIdx.x;
    v[tid] = ws[WS_ACC + (size_t)b * HIDDEN + tid];
    __syncthreads();

    for (int k = 2; k <= HIDDEN; k <<= 1) {
        for (int j = k >> 1; j > 0; j >>= 1) {
            int ixj = tid ^ j;
            if (ixj > tid) {
                float a  = v[tid];
                float bb = v[ixj];
                bool up  = (tid & k) == 0;
                if (up ? (a < bb) : (a > bb)) {
                    v[tid] = bb;
                    v[ixj] = a;
                }
            }
            __syncthreads();
        }
    }
    out[(size_t)b * HIDDEN + tid] = v[tid];
}

// ---------------------------------------------------------------- launcher
extern "C" void kernel_launch(void* const* d_in, const int* in_sizes, int n_in,
                              void* d_out, int out_size, void* d_ws, size_t ws_size,
                              hipStream_t stream) {
    const float* x  = (const float*)d_in[0];   // (64, 8192, 1)
    const float* qw = (const float*)d_in[1];   // (128,1)
    const float* qb = (const float*)d_in[2];   // (128,)
    const float* kw = (const float*)d_in[3];   // (128,1)
    // d_in[4] = k_b (cancels in softmax)
    const float* G  = (const float*)d_in[5];   // (8192, 256)
    float* out = (float*)d_out;
    float* ws  = (float*)d_ws;

    stats_kernel<<<BATCH, 256, 0, stream>>>(x, qw, qb, kw, ws);
    contract_kernel<<<dim3(CHUNKS, BGROUPS), 256, 0, stream>>>(x, G, ws);
    reduce_sort_kernel<<<BATCH, 256, 0, stream>>>(ws, out);
}

// Round 3
// 119.869 us; speedup vs baseline: 1.0621x; 1.0621x over previous
//
#include <hip/hip_runtime.h>
#include <math.h>

#define BATCH   64
#define SEQ     8192
#define NHEAD   8
#define HIDDEN  256
#define TCHUNK  64
#define CHUNKS  128                     // SEQ / TCHUNK
#define BT      16                      // batches per block
#define BGROUPS 4                       // BATCH / BT
#define SCALE   0.17677669529663687f    // 1/sqrt(32)

// ws layout (floats):
#define WS_ALPHA 0
#define WS_M     512
#define WS_RZ    1024
#define WS_ACC   1536                   // S slots of BATCH*HIDDEN floats
#define SLOT_FLOATS (BATCH * HIDDEN)    // 16384

#define CPAD 20                         // head stride in coeff row (bank-conflict-free)
#define CROW (NHEAD * CPAD)             // 160 floats per t-row
#define XPAD 65

// ---------------------------------------------------------------- kernel 1
// Per batch b: head constants A_h,C_h; alpha[b,h];
// m[b,h] = max(alpha*xmax, alpha*xmin); Z via one pass over x (8 heads at once).
__global__ void stats_kernel(const float* __restrict__ x,
                             const float* __restrict__ qw,
                             const float* __restrict__ qb,
                             const float* __restrict__ kw,
                             float* __restrict__ ws) {
    __shared__ float sA[NHEAD], sC[NHEAD];
    __shared__ float smx[4], smn[4], szz[32];
    int b   = blockIdx.x;
    int tid = threadIdx.x;
    int w   = tid >> 6;
    int lane = tid & 63;

    if (tid < 128) {
        float p1 = qw[tid] * kw[tid];
        float p2 = qb[tid] * kw[tid];
        #pragma unroll
        for (int msk = 1; msk < 16; msk <<= 1) {
            p1 += __shfl_xor(p1, msk);
            p2 += __shfl_xor(p2, msk);
        }
        if ((tid & 15) == 0) { sA[tid >> 4] = p1; sC[tid >> 4] = p2; }
    }

    const float* xb = x + (size_t)b * SEQ;
    float xr[32];
    float mx = -INFINITY, mn = INFINITY;
    #pragma unroll
    for (int i = 0; i < 32; ++i) {
        xr[i] = xb[tid + i * 256];
        mx = fmaxf(mx, xr[i]);
        mn = fminf(mn, xr[i]);
    }
    #pragma unroll
    for (int msk = 32; msk >= 1; msk >>= 1) {
        mx = fmaxf(mx, __shfl_xor(mx, msk));
        mn = fminf(mn, __shfl_xor(mn, msk));
    }
    if (lane == 0) { smx[w] = mx; smn[w] = mn; }
    __syncthreads();

    float xmax = fmaxf(fmaxf(smx[0], smx[1]), fmaxf(smx[2], smx[3]));
    float xmin = fminf(fminf(smn[0], smn[1]), fminf(smn[2], smn[3]));
    float x0 = xb[0];

    float al[NHEAD], mh[NHEAD], ls[NHEAD];
    #pragma unroll
    for (int h = 0; h < NHEAD; ++h) {
        al[h] = SCALE * (x0 * sA[h] + sC[h]);
        mh[h] = fmaxf(al[h] * xmax, al[h] * xmin);
        ls[h] = 0.f;
    }
    #pragma unroll 4
    for (int i = 0; i < 32; ++i) {
        float e = xr[i];
        #pragma unroll
        for (int h = 0; h < NHEAD; ++h)
            ls[h] += __expf(al[h] * e - mh[h]);
    }
    #pragma unroll
    for (int h = 0; h < NHEAD; ++h) {
        float v = ls[h];
        #pragma unroll
        for (int msk = 32; msk >= 1; msk >>= 1)
            v += __shfl_xor(v, msk);
        if (lane == 0) szz[w * NHEAD + h] = v;
    }
    __syncthreads();
    if (tid < NHEAD) {
        float Z = szz[tid] + szz[8 + tid] + szz[16 + tid] + szz[24 + tid];
        ws[WS_ALPHA + b * NHEAD + tid] = al[tid];
        ws[WS_M     + b * NHEAD + tid] = mh[tid];
        ws[WS_RZ    + b * NHEAD + tid] = 1.f / Z;
    }
}

// ---------------------------------------------------------------- zero
__global__ void zero_kernel(float* __restrict__ ws, int nfloats) {
    int idx = blockIdx.x * blockDim.x + threadIdx.x;
    int stride = gridDim.x * blockDim.x;
    for (int i = idx; i < nfloats; i += stride)
        ws[WS_ACC + i] = 0.f;
}

// ---------------------------------------------------------------- kernel 2
// Context contraction with 16-batch reuse of each G element.
// grid (CHUNKS, BGROUPS), 256 threads. Wave w handles t in [w*16, w*16+16),
// each lane owns 4 columns; 16 float accumulators (one per batch).
// Output: slot = chunk % S. If use_store (S==CHUNKS) plain float4 stores,
// else atomicAdd (contention = CHUNKS/S per address instead of CHUNKS).
__global__ void contract_kernel(const float* __restrict__ x,
                                const float* __restrict__ G,
                                float* __restrict__ ws,
                                int S, int use_store) {
    __shared__ float coeff[TCHUNK * CROW];     // 40 KB, padded layout
    __shared__ float xs[BT * XPAD];
    __shared__ float sal[BT * NHEAD], smm[BT * NHEAD], srz[BT * NHEAD];

    int chunk = blockIdx.x;            // 0..127
    int bg    = blockIdx.y;            // 0..3
    int b0    = bg * BT;
    int tid   = threadIdx.x;
    int w     = tid >> 6;
    int lane  = tid & 63;
    int t0    = chunk * TCHUNK;
    int slot  = chunk % S;

    if (tid < BT * NHEAD) {            // params [bi][h]
        int bi = tid >> 3, hh = tid & 7;
        int g = (b0 + bi) * NHEAD + hh;
        sal[tid] = ws[WS_ALPHA + g];
        smm[tid] = ws[WS_M + g];
        srz[tid] = ws[WS_RZ + g];
    }
    for (int i = tid; i < BT * TCHUNK; i += 256) {
        int bi = i >> 6, t = i & 63;
        xs[bi * XPAD + t] = x[(size_t)(b0 + bi) * SEQ + t0 + t];
    }
    __syncthreads();

    // coeff[t][h][bi] = exp(a*x - m) * rz * x ; fixed (bi,h) per thread
    {
        int bi = tid & 15;
        int hh = (tid >> 4) & 7;
        int p  = bi * NHEAD + hh;
        float a  = sal[p], mm = smm[p], rz = srz[p];
        int tb = tid >> 7;             // t parity
        #pragma unroll 8
        for (int j = 0; j < 32; ++j) {
            int t = tb + j * 2;
            float e = xs[bi * XPAD + t];
            coeff[t * CROW + hh * CPAD + bi] = __expf(a * e - mm) * rz * e;
        }
    }
    __syncthreads();

    int h = lane >> 3;                 // head of this lane's 4 columns
    const float* gp = G + (size_t)(t0 + w * 16) * HIDDEN + lane * 4;
    float4 g = *(const float4*)gp;
    float4 acc[BT];
    #pragma unroll
    for (int bi = 0; bi < BT; ++bi) acc[bi] = make_float4(0.f, 0.f, 0.f, 0.f);

    #pragma unroll 2
    for (int t = 0; t < 16; ++t) {
        int tn = (t + 1 < 16) ? t + 1 : 15;
        float4 gn = *(const float4*)(gp + (size_t)tn * HIDDEN);   // prefetch
        const float* cr = coeff + (w * 16 + t) * CROW + h * CPAD;
        float4 c0 = *(const float4*)(cr);
        float4 c1 = *(const float4*)(cr + 4);
        float4 c2 = *(const float4*)(cr + 8);
        float4 c3 = *(const float4*)(cr + 12);
        float cc[BT] = {c0.x, c0.y, c0.z, c0.w, c1.x, c1.y, c1.z, c1.w,
                        c2.x, c2.y, c2.z, c2.w, c3.x, c3.y, c3.z, c3.w};
        #pragma unroll
        for (int bi = 0; bi < BT; ++bi) {
            acc[bi].x = fmaf(cc[bi], g.x, acc[bi].x);
            acc[bi].y = fmaf(cc[bi], g.y, acc[bi].y);
            acc[bi].z = fmaf(cc[bi], g.z, acc[bi].z);
            acc[bi].w = fmaf(cc[bi], g.w, acc[bi].w);
        }
        g = gn;
    }

    // cross-wave reduction in LDS (reuse coeff region)
    __syncthreads();
    float* red = coeff;                // needs 2*BT*HIDDEN = 8192 floats <= 10240
    if (w >= 2) {
        float* r = red + (size_t)(w - 2) * BT * HIDDEN;
        #pragma unroll
        for (int bi = 0; bi < BT; ++bi)
            *(float4*)(r + bi * HIDDEN + lane * 4) = acc[bi];
    }
    __syncthreads();
    if (w < 2) {
        const float* r = red + (size_t)w * BT * HIDDEN;
        #pragma unroll
        for (int bi = 0; bi < BT; ++bi) {
            float4 v = *(const float4*)(r + bi * HIDDEN + lane * 4);
            acc[bi].x += v.x; acc[bi].y += v.y; acc[bi].z += v.z; acc[bi].w += v.w;
        }
    }
    __syncthreads();
    if (w == 1) {
        #pragma unroll
        for (int bi = 0; bi < BT; ++bi)
            *(float4*)(red + bi * HIDDEN + lane * 4) = acc[bi];
    }
    __syncthreads();
    if (w == 0) {
        float* slotbase = ws + WS_ACC + (size_t)slot * SLOT_FLOATS;
        #pragma unroll
        for (int bi = 0; bi < BT; ++bi) {
            float4 v = *(const float4*)(red + bi * HIDDEN + lane * 4);
            float4 r = make_float4(acc[bi].x + v.x, acc[bi].y + v.y,
                                   acc[bi].z + v.z, acc[bi].w + v.w);
            float* dst = slotbase + (size_t)(b0 + bi) * HIDDEN + lane * 4;
            if (use_store) {
                *(float4*)dst = r;
            } else {
                atomicAdd(dst + 0, r.x);
                atomicAdd(dst + 1, r.y);
                atomicAdd(dst + 2, r.z);
                atomicAdd(dst + 3, r.w);
            }
        }
    }
}

// ---------------------------------------------------------------- kernel 3
// Sum S slots per (b,c), then 256-element descending bitonic sort per batch.
__global__ void reduce_sort_kernel(const float* __restrict__ ws,
                                   float* __restrict__ out, int S) {
    __shared__ float v[HIDDEN];
    int b   = blockIdx.x;
    int tid = threadIdx.x;
    float s = 0.f;
    for (int sl = 0; sl < S; ++sl)
        s += ws[WS_ACC + (size_t)sl * SLOT_FLOATS + (size_t)b * HIDDEN + tid];
    v[tid] = s;
    __syncthreads();

    for (int k = 2; k <= HIDDEN; k <<= 1) {
        for (int j = k >> 1; j > 0; j >>= 1) {
            int ixj = tid ^ j;
            if (ixj > tid) {
                float a  = v[tid];
                float bb = v[ixj];
                bool up  = (tid & k) == 0;
                if (up ? (a < bb) : (a > bb)) {
                    v[tid] = bb;
                    v[ixj] = a;
                }
            }
            __syncthreads();
        }
    }
    out[(size_t)b * HIDDEN + tid] = v[tid];
}

// ---------------------------------------------------------------- launcher
extern "C" void kernel_launch(void* const* d_in, const int* in_sizes, int n_in,
                              void* d_out, int out_size, void* d_ws, size_t ws_size,
                              hipStream_t stream) {
    const float* x  = (const float*)d_in[0];   // (64, 8192, 1)
    const float* qw = (const float*)d_in[1];   // (128,1)
    const float* qb = (const float*)d_in[2];   // (128,)
    const float* kw = (const float*)d_in[3];   // (128,1)
    // d_in[4] = k_b (cancels in softmax)
    const float* G  = (const float*)d_in[5];   // (8192, 256)
    float* out = (float*)d_out;
    float* ws  = (float*)d_ws;

    // slot count sized to workspace: S slots of 64KB partials
    long avail = (long)(ws_size / 4) - WS_ACC;
    int S = (int)(avail / SLOT_FLOATS);
    if (S > CHUNKS) S = CHUNKS;
    if (S < 1) S = 1;
    int use_store = (S == CHUNKS) ? 1 : 0;

    stats_kernel<<<BATCH, 256, 0, stream>>>(x, qw, qb, kw, ws);
    if (!use_store)
        zero_kernel<<<256, 256, 0, stream>>>(ws, S * SLOT_FLOATS);
    contract_kernel<<<dim3(CHUNKS, BGROUPS), 256, 0, stream>>>(x, G, ws, S, use_store);
    reduce_sort_kernel<<<BATCH, 256, 0, stream>>>(ws, out, S);
}

// Round 4
// 118.793 us; speedup vs baseline: 1.0717x; 1.0091x over previous
//
#include <hip/hip_runtime.h>
#include <math.h>

#define BATCH   64
#define SEQ     8192
#define NHEAD   8
#define HIDDEN  256
#define TCHUNK  64
#define CHUNKS  128                     // SEQ / TCHUNK
#define BT      16                      // batches per block
#define BGROUPS 4                       // BATCH / BT
#define SCALE   0.17677669529663687f    // 1/sqrt(32)

// ws layout (floats):
#define WS_ALPHA 0
#define WS_M     512
#define WS_RZ    1024
#define WS_ACC   1536                   // S slots of BATCH*HIDDEN floats
#define SLOT_FLOATS (BATCH * HIDDEN)    // 16384

#define CPAD 20                         // head stride in coeff row (bank-conflict-free)
#define CROW (NHEAD * CPAD)             // 160 floats per t-row
#define XPAD 65

// ---------------------------------------------------------------- kernel 1
// Per batch b: head constants A_h,C_h; alpha[b,h];
// m[b,h] = max(alpha*xmax, alpha*xmin); Z via one pass over x (8 heads at once).
__global__ void __launch_bounds__(256)
stats_kernel(const float* __restrict__ x,
             const float* __restrict__ qw,
             const float* __restrict__ qb,
             const float* __restrict__ kw,
             float* __restrict__ ws) {
    __shared__ float sA[NHEAD], sC[NHEAD];
    __shared__ float smx[4], smn[4], szz[32];
    int b   = blockIdx.x;
    int tid = threadIdx.x;
    int w   = tid >> 6;
    int lane = tid & 63;

    if (tid < 128) {
        float p1 = qw[tid] * kw[tid];
        float p2 = qb[tid] * kw[tid];
        #pragma unroll
        for (int msk = 1; msk < 16; msk <<= 1) {
            p1 += __shfl_xor(p1, msk);
            p2 += __shfl_xor(p2, msk);
        }
        if ((tid & 15) == 0) { sA[tid >> 4] = p1; sC[tid >> 4] = p2; }
    }

    const float* xb = x + (size_t)b * SEQ;
    float xr[32];
    float mx = -INFINITY, mn = INFINITY;
    #pragma unroll
    for (int i = 0; i < 32; ++i) {
        xr[i] = xb[tid + i * 256];
        mx = fmaxf(mx, xr[i]);
        mn = fminf(mn, xr[i]);
    }
    #pragma unroll
    for (int msk = 32; msk >= 1; msk >>= 1) {
        mx = fmaxf(mx, __shfl_xor(mx, msk));
        mn = fminf(mn, __shfl_xor(mn, msk));
    }
    if (lane == 0) { smx[w] = mx; smn[w] = mn; }
    __syncthreads();

    float xmax = fmaxf(fmaxf(smx[0], smx[1]), fmaxf(smx[2], smx[3]));
    float xmin = fminf(fminf(smn[0], smn[1]), fminf(smn[2], smn[3]));
    float x0 = xb[0];

    float al[NHEAD], mh[NHEAD], ls[NHEAD];
    #pragma unroll
    for (int h = 0; h < NHEAD; ++h) {
        al[h] = SCALE * (x0 * sA[h] + sC[h]);
        mh[h] = fmaxf(al[h] * xmax, al[h] * xmin);
        ls[h] = 0.f;
    }
    #pragma unroll 4
    for (int i = 0; i < 32; ++i) {
        float e = xr[i];
        #pragma unroll
        for (int h = 0; h < NHEAD; ++h)
            ls[h] += __expf(al[h] * e - mh[h]);
    }
    #pragma unroll
    for (int h = 0; h < NHEAD; ++h) {
        float v = ls[h];
        #pragma unroll
        for (int msk = 32; msk >= 1; msk >>= 1)
            v += __shfl_xor(v, msk);
        if (lane == 0) szz[w * NHEAD + h] = v;
    }
    __syncthreads();
    if (tid < NHEAD) {
        float Z = szz[tid] + szz[8 + tid] + szz[16 + tid] + szz[24 + tid];
        ws[WS_ALPHA + b * NHEAD + tid] = al[tid];
        ws[WS_M     + b * NHEAD + tid] = mh[tid];
        ws[WS_RZ    + b * NHEAD + tid] = 1.f / Z;
    }
}

// ---------------------------------------------------------------- zero
__global__ void __launch_bounds__(256)
zero_kernel(float* __restrict__ ws, int nfloats) {
    int idx = blockIdx.x * blockDim.x + threadIdx.x;
    int stride = gridDim.x * blockDim.x;
    for (int i = idx; i < nfloats; i += stride)
        ws[WS_ACC + i] = 0.f;
}

// ---------------------------------------------------------------- kernel 2
// Context contraction with 16-batch reuse of each G element.
// grid (CHUNKS, BGROUPS), 256 threads. Wave w handles t in [w*16, w*16+16),
// each lane owns 4 columns; 16 float4 accumulators (one per batch).
// __launch_bounds__(256,2): 2 waves/EU -> VGPR cap 256, accumulators stay
// in registers (R2/R3 spilled at VGPR_Count=52 -> ~1GB scratch traffic).
__global__ void __launch_bounds__(256, 2)
contract_kernel(const float* __restrict__ x,
                const float* __restrict__ G,
                float* __restrict__ ws,
                int S, int use_store) {
    __shared__ float coeff[TCHUNK * CROW];     // 40 KB, padded layout
    __shared__ float xs[BT * XPAD];
    __shared__ float sal[BT * NHEAD], smm[BT * NHEAD], srz[BT * NHEAD];

    int chunk = blockIdx.x;            // 0..127
    int bg    = blockIdx.y;            // 0..3
    int b0    = bg * BT;
    int tid   = threadIdx.x;
    int w     = tid >> 6;
    int lane  = tid & 63;
    int t0    = chunk * TCHUNK;
    int slot  = chunk % S;

    if (tid < BT * NHEAD) {            // params [bi][h]
        int bi = tid >> 3, hh = tid & 7;
        int g = (b0 + bi) * NHEAD + hh;
        sal[tid] = ws[WS_ALPHA + g];
        smm[tid] = ws[WS_M + g];
        srz[tid] = ws[WS_RZ + g];
    }
    for (int i = tid; i < BT * TCHUNK; i += 256) {
        int bi = i >> 6, t = i & 63;
        xs[bi * XPAD + t] = x[(size_t)(b0 + bi) * SEQ + t0 + t];
    }
    __syncthreads();

    // coeff[t][h][bi] = exp(a*x - m) * rz * x ; fixed (bi,h) per thread
    {
        int bi = tid & 15;
        int hh = (tid >> 4) & 7;
        int p  = bi * NHEAD + hh;
        float a  = sal[p], mm = smm[p], rz = srz[p];
        int tb = tid >> 7;             // t parity
        #pragma unroll 8
        for (int j = 0; j < 32; ++j) {
            int t = tb + j * 2;
            float e = xs[bi * XPAD + t];
            coeff[t * CROW + hh * CPAD + bi] = __expf(a * e - mm) * rz * e;
        }
    }
    __syncthreads();

    int h = lane >> 3;                 // head of this lane's 4 columns
    const float* gp = G + (size_t)(t0 + w * 16) * HIDDEN + lane * 4;
    float4 g = *(const float4*)gp;
    float4 acc[BT];
    #pragma unroll
    for (int bi = 0; bi < BT; ++bi) acc[bi] = make_float4(0.f, 0.f, 0.f, 0.f);

    #pragma unroll 4
    for (int t = 0; t < 16; ++t) {
        int tn = (t + 1 < 16) ? t + 1 : 15;
        float4 gn = *(const float4*)(gp + (size_t)tn * HIDDEN);   // prefetch
        const float* cr = coeff + (w * 16 + t) * CROW + h * CPAD;
        float4 c0 = *(const float4*)(cr);
        float4 c1 = *(const float4*)(cr + 4);
        float4 c2 = *(const float4*)(cr + 8);
        float4 c3 = *(const float4*)(cr + 12);
        float cc[BT] = {c0.x, c0.y, c0.z, c0.w, c1.x, c1.y, c1.z, c1.w,
                        c2.x, c2.y, c2.z, c2.w, c3.x, c3.y, c3.z, c3.w};
        #pragma unroll
        for (int bi = 0; bi < BT; ++bi) {
            acc[bi].x = fmaf(cc[bi], g.x, acc[bi].x);
            acc[bi].y = fmaf(cc[bi], g.y, acc[bi].y);
            acc[bi].z = fmaf(cc[bi], g.z, acc[bi].z);
            acc[bi].w = fmaf(cc[bi], g.w, acc[bi].w);
        }
        g = gn;
    }

    // cross-wave reduction in LDS (reuse coeff region)
    __syncthreads();
    float* red = coeff;                // needs 2*BT*HIDDEN = 8192 floats <= 10240
    if (w >= 2) {
        float* r = red + (size_t)(w - 2) * BT * HIDDEN;
        #pragma unroll
        for (int bi = 0; bi < BT; ++bi)
            *(float4*)(r + bi * HIDDEN + lane * 4) = acc[bi];
    }
    __syncthreads();
    if (w < 2) {
        const float* r = red + (size_t)w * BT * HIDDEN;
        #pragma unroll
        for (int bi = 0; bi < BT; ++bi) {
            float4 v = *(const float4*)(r + bi * HIDDEN + lane * 4);
            acc[bi].x += v.x; acc[bi].y += v.y; acc[bi].z += v.z; acc[bi].w += v.w;
        }
    }
    __syncthreads();
    if (w == 1) {
        #pragma unroll
        for (int bi = 0; bi < BT; ++bi)
            *(float4*)(red + bi * HIDDEN + lane * 4) = acc[bi];
    }
    __syncthreads();
    if (w == 0) {
        float* slotbase = ws + WS_ACC + (size_t)slot * SLOT_FLOATS;
        #pragma unroll
        for (int bi = 0; bi < BT; ++bi) {
            float4 v = *(const float4*)(red + bi * HIDDEN + lane * 4);
            float4 r = make_float4(acc[bi].x + v.x, acc[bi].y + v.y,
                                   acc[bi].z + v.z, acc[bi].w + v.w);
            float* dst = slotbase + (size_t)(b0 + bi) * HIDDEN + lane * 4;
            if (use_store) {
                *(float4*)dst = r;
            } else {
                atomicAdd(dst + 0, r.x);
                atomicAdd(dst + 1, r.y);
                atomicAdd(dst + 2, r.z);
                atomicAdd(dst + 3, r.w);
            }
        }
    }
}

// ---------------------------------------------------------------- kernel 3
// Sum S slots per (b,c), then 256-element descending bitonic sort per batch.
__global__ void __launch_bounds__(256)
reduce_sort_kernel(const float* __restrict__ ws,
                   float* __restrict__ out, int S) {
    __shared__ float v[HIDDEN];
    int b   = blockIdx.x;
    int tid = threadIdx.x;
    float s = 0.f;
    for (int sl = 0; sl < S; ++sl)
        s += ws[WS_ACC + (size_t)sl * SLOT_FLOATS + (size_t)b * HIDDEN + tid];
    v[tid] = s;
    __syncthreads();

    for (int k = 2; k <= HIDDEN; k <<= 1) {
        for (int j = k >> 1; j > 0; j >>= 1) {
            int ixj = tid ^ j;
            if (ixj > tid) {
                float a  = v[tid];
                float bb = v[ixj];
                bool up  = (tid & k) == 0;
                if (up ? (a < bb) : (a > bb)) {
                    v[tid] = bb;
                    v[ixj] = a;
                }
            }
            __syncthreads();
        }
    }
    out[(size_t)b * HIDDEN + tid] = v[tid];
}

// ---------------------------------------------------------------- launcher
extern "C" void kernel_launch(void* const* d_in, const int* in_sizes, int n_in,
                              void* d_out, int out_size, void* d_ws, size_t ws_size,
                              hipStream_t stream) {
    const float* x  = (const float*)d_in[0];   // (64, 8192, 1)
    const float* qw = (const float*)d_in[1];   // (128,1)
    const float* qb = (const float*)d_in[2];   // (128,)
    const float* kw = (const float*)d_in[3];   // (128,1)
    // d_in[4] = k_b (cancels in softmax)
    const float* G  = (const float*)d_in[5];   // (8192, 256)
    float* out = (float*)d_out;
    float* ws  = (float*)d_ws;

    // slot count sized to workspace: S slots of 64KB partials
    long avail = (long)(ws_size / 4) - WS_ACC;
    int S = (int)(avail / SLOT_FLOATS);
    if (S > CHUNKS) S = CHUNKS;
    if (S < 1) S = 1;
    int use_store = (S == CHUNKS) ? 1 : 0;

    stats_kernel<<<BATCH, 256, 0, stream>>>(x, qw, qb, kw, ws);
    if (!use_store)
        zero_kernel<<<256, 256, 0, stream>>>(ws, S * SLOT_FLOATS);
    contract_kernel<<<dim3(CHUNKS, BGROUPS), 256, 0, stream>>>(x, G, ws, S, use_store);
    reduce_sort_kernel<<<BATCH, 256, 0, stream>>>(ws, out, S);
}

// Round 5
// 97.292 us; speedup vs baseline: 1.3086x; 1.2210x over previous
//
#include <hip/hip_runtime.h>
#include <math.h>

#define BATCH   64
#define SEQ     8192
#define NHEAD   8
#define HIDDEN  256
#define TCHUNK  64
#define CHUNKS  128                     // SEQ / TCHUNK
#define BT      8                       // batches per block
#define BGROUPS 8                       // BATCH / BT
#define SCALE   0.17677669529663687f    // 1/sqrt(32)

// ws layout (floats):
#define WS_ALPHA 0
#define WS_M     512
#define WS_RZ    1024
#define WS_ACC   1536                   // S slots of BATCH*HIDDEN floats
#define SLOT_FLOATS (BATCH * HIDDEN)    // 16384

#define CPADB 12                        // bi-stride block per head (8 + 4 pad)
#define CROW  (NHEAD * CPADB)           // 96 floats per t-row
#define XPAD  68

// ---------------------------------------------------------------- kernel 1
__global__ void __launch_bounds__(256)
stats_kernel(const float* __restrict__ x,
             const float* __restrict__ qw,
             const float* __restrict__ qb,
             const float* __restrict__ kw,
             float* __restrict__ ws) {
    __shared__ float sA[NHEAD], sC[NHEAD];
    __shared__ float smx[4], smn[4], szz[32];
    int b   = blockIdx.x;
    int tid = threadIdx.x;
    int w   = tid >> 6;
    int lane = tid & 63;

    if (tid < 128) {
        float p1 = qw[tid] * kw[tid];
        float p2 = qb[tid] * kw[tid];
        #pragma unroll
        for (int msk = 1; msk < 16; msk <<= 1) {
            p1 += __shfl_xor(p1, msk);
            p2 += __shfl_xor(p2, msk);
        }
        if ((tid & 15) == 0) { sA[tid >> 4] = p1; sC[tid >> 4] = p2; }
    }

    const float* xb = x + (size_t)b * SEQ;
    float xr[32];
    float mx = -INFINITY, mn = INFINITY;
    #pragma unroll
    for (int i = 0; i < 32; ++i) {
        xr[i] = xb[tid + i * 256];
        mx = fmaxf(mx, xr[i]);
        mn = fminf(mn, xr[i]);
    }
    #pragma unroll
    for (int msk = 32; msk >= 1; msk >>= 1) {
        mx = fmaxf(mx, __shfl_xor(mx, msk));
        mn = fminf(mn, __shfl_xor(mn, msk));
    }
    if (lane == 0) { smx[w] = mx; smn[w] = mn; }
    __syncthreads();

    float xmax = fmaxf(fmaxf(smx[0], smx[1]), fmaxf(smx[2], smx[3]));
    float xmin = fminf(fminf(smn[0], smn[1]), fminf(smn[2], smn[3]));
    float x0 = xb[0];

    float al[NHEAD], mh[NHEAD], ls[NHEAD];
    #pragma unroll
    for (int h = 0; h < NHEAD; ++h) {
        al[h] = SCALE * (x0 * sA[h] + sC[h]);
        mh[h] = fmaxf(al[h] * xmax, al[h] * xmin);
        ls[h] = 0.f;
    }
    #pragma unroll 4
    for (int i = 0; i < 32; ++i) {
        float e = xr[i];
        #pragma unroll
        for (int h = 0; h < NHEAD; ++h)
            ls[h] += __expf(al[h] * e - mh[h]);
    }
    #pragma unroll
    for (int h = 0; h < NHEAD; ++h) {
        float v = ls[h];
        #pragma unroll
        for (int msk = 32; msk >= 1; msk >>= 1)
            v += __shfl_xor(v, msk);
        if (lane == 0) szz[w * NHEAD + h] = v;
    }
    __syncthreads();
    if (tid < NHEAD) {
        float Z = szz[tid] + szz[8 + tid] + szz[16 + tid] + szz[24 + tid];
        ws[WS_ALPHA + b * NHEAD + tid] = al[tid];
        ws[WS_M     + b * NHEAD + tid] = mh[tid];
        ws[WS_RZ    + b * NHEAD + tid] = 1.f / Z;
    }
}

// ---------------------------------------------------------------- zero
__global__ void __launch_bounds__(256)
zero_kernel(float* __restrict__ ws, int nfloats) {
    int idx = blockIdx.x * blockDim.x + threadIdx.x;
    int stride = gridDim.x * blockDim.x;
    for (int i = idx; i < nfloats; i += stride)
        ws[WS_ACC + i] = 0.f;
}

// ---------------------------------------------------------------- kernel 2
// grid (CHUNKS=128, BGROUPS=8) = 1024 blocks (4/CU), 256 threads.
// Wave w handles t in [w*16, w*16+16); lane owns cols lane*4..+3 (head = lane>>3);
// 8 float4 accumulators (one per batch). LDS ~28KB, VGPR capped 128 via (256,4).
__global__ void __launch_bounds__(256, 4)
contract_kernel(const float* __restrict__ x,
                const float* __restrict__ G,
                float* __restrict__ ws,
                int S, int use_store) {
    __shared__ float coeff[TCHUNK * CROW];     // 64*96 = 6144 floats (24KB)
    __shared__ float xs[BT * XPAD];            // 544 floats
    __shared__ float sal[BT * NHEAD], smm[BT * NHEAD], srz[BT * NHEAD];

    int chunk = blockIdx.x;            // 0..127
    int bg    = blockIdx.y;            // 0..7
    int b0    = bg * BT;
    int tid   = threadIdx.x;
    int w     = tid >> 6;
    int lane  = tid & 63;
    int t0    = chunk * TCHUNK;
    int slot  = chunk % S;

    if (tid < BT * NHEAD) {            // params [bi][h], stride NHEAD
        int bi = tid >> 3, hh = tid & 7;
        int g = (b0 + bi) * NHEAD + hh;
        sal[tid] = ws[WS_ALPHA + g];
        smm[tid] = ws[WS_M + g];
        srz[tid] = ws[WS_RZ + g];
    }
    // stage x[b0..b0+8)[t0..t0+64) -> xs
    for (int i = tid; i < BT * TCHUNK; i += 256) {
        int bi = i >> 6, t = i & 63;
        xs[bi * XPAD + t] = x[(size_t)(b0 + bi) * SEQ + t0 + t];
    }
    __syncthreads();

    // coeff[t][h*12+bi] = exp(a*x-m)*rz*x ; fixed (bi,hh) per thread,
    // each wave fills its own t-range [w*16, w*16+16)
    {
        int bi = tid & 7;
        int hh = (tid >> 3) & 7;
        int p  = bi * NHEAD + hh;
        float a  = sal[p], mm = smm[p], rz = srz[p];
        #pragma unroll
        for (int j = 0; j < 16; ++j) {
            int t = w * 16 + j;
            float e = xs[bi * XPAD + t];
            coeff[t * CROW + hh * CPADB + bi] = __expf(a * e - mm) * rz * e;
        }
    }
    __syncthreads();

    int h = lane >> 3;                 // head of this lane's 4 columns
    const float* gp = G + (size_t)(t0 + w * 16) * HIDDEN + lane * 4;
    float4 g = *(const float4*)gp;
    float4 acc[BT];
    #pragma unroll
    for (int bi = 0; bi < BT; ++bi) acc[bi] = make_float4(0.f, 0.f, 0.f, 0.f);

    #pragma unroll
    for (int t = 0; t < 16; ++t) {
        int tn = (t + 1 < 16) ? t + 1 : 15;
        float4 gn = *(const float4*)(gp + (size_t)tn * HIDDEN);   // prefetch
        const float* cr = coeff + (w * 16 + t) * CROW + h * CPADB;
        float4 c0 = *(const float4*)(cr);
        float4 c1 = *(const float4*)(cr + 4);
        float cc[BT] = {c0.x, c0.y, c0.z, c0.w, c1.x, c1.y, c1.z, c1.w};
        #pragma unroll
        for (int bi = 0; bi < BT; ++bi) {
            acc[bi].x = fmaf(cc[bi], g.x, acc[bi].x);
            acc[bi].y = fmaf(cc[bi], g.y, acc[bi].y);
            acc[bi].z = fmaf(cc[bi], g.z, acc[bi].z);
            acc[bi].w = fmaf(cc[bi], g.w, acc[bi].w);
        }
        g = gn;
    }

    // cross-wave reduction in LDS (reuse coeff region; needs 2*8*256=4096<=6144)
    __syncthreads();
    float* red = coeff;
    if (w >= 2) {
        float* r = red + (size_t)(w - 2) * BT * HIDDEN;
        #pragma unroll
        for (int bi = 0; bi < BT; ++bi)
            *(float4*)(r + bi * HIDDEN + lane * 4) = acc[bi];
    }
    __syncthreads();
    if (w < 2) {
        const float* r = red + (size_t)w * BT * HIDDEN;
        #pragma unroll
        for (int bi = 0; bi < BT; ++bi) {
            float4 v = *(const float4*)(r + bi * HIDDEN + lane * 4);
            acc[bi].x += v.x; acc[bi].y += v.y; acc[bi].z += v.z; acc[bi].w += v.w;
        }
    }
    __syncthreads();
    if (w == 1) {
        #pragma unroll
        for (int bi = 0; bi < BT; ++bi)
            *(float4*)(red + bi * HIDDEN + lane * 4) = acc[bi];
    }
    __syncthreads();
    if (w == 0) {
        float* slotbase = ws + WS_ACC + (size_t)slot * SLOT_FLOATS;
        #pragma unroll
        for (int bi = 0; bi < BT; ++bi) {
            float4 v = *(const float4*)(red + bi * HIDDEN + lane * 4);
            float4 r = make_float4(acc[bi].x + v.x, acc[bi].y + v.y,
                                   acc[bi].z + v.z, acc[bi].w + v.w);
            float* dst = slotbase + (size_t)(b0 + bi) * HIDDEN + lane * 4;
            if (use_store) {
                *(float4*)dst = r;
            } else {
                atomicAdd(dst + 0, r.x);
                atomicAdd(dst + 1, r.y);
                atomicAdd(dst + 2, r.z);
                atomicAdd(dst + 3, r.w);
            }
        }
    }
}

// ---------------------------------------------------------------- kernel 3
__global__ void __launch_bounds__(256)
reduce_sort_kernel(const float* __restrict__ ws,
                   float* __restrict__ out, int S) {
    __shared__ float v[HIDDEN];
    int b   = blockIdx.x;
    int tid = threadIdx.x;
    float s0 = 0.f, s1 = 0.f, s2 = 0.f, s3 = 0.f;
    int sl = 0;
    for (; sl + 4 <= S; sl += 4) {
        s0 += ws[WS_ACC + (size_t)(sl + 0) * SLOT_FLOATS + (size_t)b * HIDDEN + tid];
        s1 += ws[WS_ACC + (size_t)(sl + 1) * SLOT_FLOATS + (size_t)b * HIDDEN + tid];
        s2 += ws[WS_ACC + (size_t)(sl + 2) * SLOT_FLOATS + (size_t)b * HIDDEN + tid];
        s3 += ws[WS_ACC + (size_t)(sl + 3) * SLOT_FLOATS + (size_t)b * HIDDEN + tid];
    }
    for (; sl < S; ++sl)
        s0 += ws[WS_ACC + (size_t)sl * SLOT_FLOATS + (size_t)b * HIDDEN + tid];
    v[tid] = (s0 + s1) + (s2 + s3);
    __syncthreads();

    for (int k = 2; k <= HIDDEN; k <<= 1) {
        for (int j = k >> 1; j > 0; j >>= 1) {
            int ixj = tid ^ j;
            if (ixj > tid) {
                float a  = v[tid];
                float bb = v[ixj];
                bool up  = (tid & k) == 0;
                if (up ? (a < bb) : (a > bb)) {
                    v[tid] = bb;
                    v[ixj] = a;
                }
            }
            __syncthreads();
        }
    }
    out[(size_t)b * HIDDEN + tid] = v[tid];
}

// ---------------------------------------------------------------- launcher
extern "C" void kernel_launch(void* const* d_in, const int* in_sizes, int n_in,
                              void* d_out, int out_size, void* d_ws, size_t ws_size,
                              hipStream_t stream) {
    const float* x  = (const float*)d_in[0];   // (64, 8192, 1)
    const float* qw = (const float*)d_in[1];   // (128,1)
    const float* qb = (const float*)d_in[2];   // (128,)
    const float* kw = (const float*)d_in[3];   // (128,1)
    // d_in[4] = k_b (cancels in softmax)
    const float* G  = (const float*)d_in[5];   // (8192, 256)
    float* out = (float*)d_out;
    float* ws  = (float*)d_ws;

    long avail = (long)(ws_size / 4) - WS_ACC;
    int S = (int)(avail / SLOT_FLOATS);
    if (S > CHUNKS) S = CHUNKS;
    if (S < 1) S = 1;
    int use_store = (S == CHUNKS) ? 1 : 0;

    stats_kernel<<<BATCH, 256, 0, stream>>>(x, qw, qb, kw, ws);
    if (!use_store)
        zero_kernel<<<256, 256, 0, stream>>>(ws, S * SLOT_FLOATS);
    contract_kernel<<<dim3(CHUNKS, BGROUPS), 256, 0, stream>>>(x, G, ws, S, use_store);
    reduce_sort_kernel<<<BATCH, 256, 0, stream>>>(ws, out, S);
}

// Round 6
// 91.314 us; speedup vs baseline: 1.3942x; 1.0655x over previous
//
#include <hip/hip_runtime.h>
#include <math.h>

#define BATCH   64
#define SEQ     8192
#define NHEAD   8
#define HIDDEN  256
#define TCHUNK  64
#define CHUNKS  128                     // SEQ / TCHUNK
#define BT      4                       // batches per block
#define BGROUPS 16                      // BATCH / BT
#define SCALE   0.17677669529663687f    // 1/sqrt(32)

// ws layout (floats):
#define WS_ALPHA 0
#define WS_M     512
#define WS_RZ    1024
#define WS_ACC   1536                   // S slots of BATCH*HIDDEN floats
#define SLOT_FLOATS (BATCH * HIDDEN)    // 16384

#define CROW  (NHEAD * BT)              // 32 floats per t-row, pad-free conflict-free
#define XPAD  68

// ---------------------------------------------------------------- kernel 1
__global__ void __launch_bounds__(256)
stats_kernel(const float* __restrict__ x,
             const float* __restrict__ qw,
             const float* __restrict__ qb,
             const float* __restrict__ kw,
             float* __restrict__ ws) {
    __shared__ float sA[NHEAD], sC[NHEAD];
    __shared__ float smx[4], smn[4], szz[32];
    int b   = blockIdx.x;
    int tid = threadIdx.x;
    int w   = tid >> 6;
    int lane = tid & 63;

    if (tid < 128) {
        float p1 = qw[tid] * kw[tid];
        float p2 = qb[tid] * kw[tid];
        #pragma unroll
        for (int msk = 1; msk < 16; msk <<= 1) {
            p1 += __shfl_xor(p1, msk);
            p2 += __shfl_xor(p2, msk);
        }
        if ((tid & 15) == 0) { sA[tid >> 4] = p1; sC[tid >> 4] = p2; }
    }

    const float* xb = x + (size_t)b * SEQ;
    float xr[32];
    float mx = -INFINITY, mn = INFINITY;
    #pragma unroll
    for (int i = 0; i < 32; ++i) {
        xr[i] = xb[tid + i * 256];
        mx = fmaxf(mx, xr[i]);
        mn = fminf(mn, xr[i]);
    }
    #pragma unroll
    for (int msk = 32; msk >= 1; msk >>= 1) {
        mx = fmaxf(mx, __shfl_xor(mx, msk));
        mn = fminf(mn, __shfl_xor(mn, msk));
    }
    if (lane == 0) { smx[w] = mx; smn[w] = mn; }
    __syncthreads();

    float xmax = fmaxf(fmaxf(smx[0], smx[1]), fmaxf(smx[2], smx[3]));
    float xmin = fminf(fminf(smn[0], smn[1]), fminf(smn[2], smn[3]));
    float x0 = xb[0];

    float al[NHEAD], mh[NHEAD], ls[NHEAD];
    #pragma unroll
    for (int h = 0; h < NHEAD; ++h) {
        al[h] = SCALE * (x0 * sA[h] + sC[h]);
        mh[h] = fmaxf(al[h] * xmax, al[h] * xmin);
        ls[h] = 0.f;
    }
    #pragma unroll 4
    for (int i = 0; i < 32; ++i) {
        float e = xr[i];
        #pragma unroll
        for (int h = 0; h < NHEAD; ++h)
            ls[h] += __expf(al[h] * e - mh[h]);
    }
    #pragma unroll
    for (int h = 0; h < NHEAD; ++h) {
        float v = ls[h];
        #pragma unroll
        for (int msk = 32; msk >= 1; msk >>= 1)
            v += __shfl_xor(v, msk);
        if (lane == 0) szz[w * NHEAD + h] = v;
    }
    __syncthreads();
    if (tid < NHEAD) {
        float Z = szz[tid] + szz[8 + tid] + szz[16 + tid] + szz[24 + tid];
        ws[WS_ALPHA + b * NHEAD + tid] = al[tid];
        ws[WS_M     + b * NHEAD + tid] = mh[tid];
        ws[WS_RZ    + b * NHEAD + tid] = 1.f / Z;
    }
}

// ---------------------------------------------------------------- zero (atomic fallback only)
__global__ void __launch_bounds__(256)
zero_kernel(float* __restrict__ ws, int nfloats) {
    int idx = blockIdx.x * blockDim.x + threadIdx.x;
    int stride = gridDim.x * blockDim.x;
    for (int i = idx; i < nfloats; i += stride)
        ws[WS_ACC + i] = 0.f;
}

// ---------------------------------------------------------------- kernel 2
// grid (CHUNKS=128, BGROUPS=16) = 2048 blocks, 256 threads, ~9.5KB LDS.
// Target ~56 VGPR -> 8 waves/SIMD residency (HW max 32 waves/CU).
// Wave w: t in [w*16,(w+1)*16); lane owns cols lane*4..+3 (head = lane>>3);
// 4 float4 accumulators (one per batch); 2-deep G prefetch.
__global__ void __launch_bounds__(256, 4)
contract_kernel(const float* __restrict__ x,
                const float* __restrict__ G,
                float* __restrict__ ws,
                int S, int use_store) {
    __shared__ float coeff[TCHUNK * CROW];     // 2048 floats (8KB)
    __shared__ float xs[BT * XPAD];
    __shared__ float sal[BT * NHEAD], smm[BT * NHEAD], srz[BT * NHEAD];

    int chunk = blockIdx.x;            // 0..127
    int bg    = blockIdx.y;            // 0..15
    int b0    = bg * BT;
    int tid   = threadIdx.x;
    int w     = tid >> 6;
    int lane  = tid & 63;
    int t0    = chunk * TCHUNK;
    int slot  = chunk % S;

    if (tid < BT * NHEAD) {            // 32 params [bi][h]
        int bi = tid >> 3, hh = tid & 7;
        int g = (b0 + bi) * NHEAD + hh;
        sal[tid] = ws[WS_ALPHA + g];
        smm[tid] = ws[WS_M + g];
        srz[tid] = ws[WS_RZ + g];
    }
    {   // stage x[b0..b0+4)[t0..t0+64) -> xs (256 loads, one per thread)
        int bi = tid >> 6, t = tid & 63;
        xs[bi * XPAD + t] = x[(size_t)(b0 + bi) * SEQ + t0 + t];
    }
    __syncthreads();

    // coeff[t][hh*4+bi] = exp(a*x-m)*rz*x ; 8 t per thread
    {
        int bi  = lane & 3;
        int hh  = (lane >> 2) & 7;
        int sub = lane >> 5;           // 0/1: which 8-t half of the wave's range
        int p   = bi * NHEAD + hh;
        float a  = sal[p], mm = smm[p], rz = srz[p];
        #pragma unroll
        for (int j = 0; j < 8; ++j) {
            int t = w * 16 + sub * 8 + j;
            float e = xs[bi * XPAD + t];
            coeff[t * CROW + hh * 4 + bi] = __expf(a * e - mm) * rz * e;
        }
    }
    __syncthreads();

    int h = lane >> 3;                 // head of this lane's 4 columns
    const float* gp = G + (size_t)(t0 + w * 16) * HIDDEN + lane * 4;
    float4 g0 = *(const float4*)gp;
    float4 g1 = *(const float4*)(gp + HIDDEN);
    float4 acc[BT];
    #pragma unroll
    for (int bi = 0; bi < BT; ++bi) acc[bi] = make_float4(0.f, 0.f, 0.f, 0.f);

    #pragma unroll
    for (int t = 0; t < 16; ++t) {
        float4 gn = (t + 2 < 16) ? *(const float4*)(gp + (size_t)(t + 2) * HIDDEN)
                                 : g1;                       // 2-deep prefetch
        float4 c = *(const float4*)(coeff + (w * 16 + t) * CROW + h * 4);
        acc[0].x = fmaf(c.x, g0.x, acc[0].x);
        acc[0].y = fmaf(c.x, g0.y, acc[0].y);
        acc[0].z = fmaf(c.x, g0.z, acc[0].z);
        acc[0].w = fmaf(c.x, g0.w, acc[0].w);
        acc[1].x = fmaf(c.y, g0.x, acc[1].x);
        acc[1].y = fmaf(c.y, g0.y, acc[1].y);
        acc[1].z = fmaf(c.y, g0.z, acc[1].z);
        acc[1].w = fmaf(c.y, g0.w, acc[1].w);
        acc[2].x = fmaf(c.z, g0.x, acc[2].x);
        acc[2].y = fmaf(c.z, g0.y, acc[2].y);
        acc[2].z = fmaf(c.z, g0.z, acc[2].z);
        acc[2].w = fmaf(c.z, g0.w, acc[2].w);
        acc[3].x = fmaf(c.w, g0.x, acc[3].x);
        acc[3].y = fmaf(c.w, g0.y, acc[3].y);
        acc[3].z = fmaf(c.w, g0.z, acc[3].z);
        acc[3].w = fmaf(c.w, g0.w, acc[3].w);
        g0 = g1; g1 = gn;
    }

    // cross-wave reduction (reuse coeff: needs 2*BT*HIDDEN = 2048 floats, exact fit)
    __syncthreads();
    float* red = coeff;
    if (w >= 2) {
        float* r = red + (size_t)(w - 2) * BT * HIDDEN;
        #pragma unroll
        for (int bi = 0; bi < BT; ++bi)
            *(float4*)(r + bi * HIDDEN + lane * 4) = acc[bi];
    }
    __syncthreads();
    if (w < 2) {
        const float* r = red + (size_t)w * BT * HIDDEN;
        #pragma unroll
        for (int bi = 0; bi < BT; ++bi) {
            float4 v = *(const float4*)(r + bi * HIDDEN + lane * 4);
            acc[bi].x += v.x; acc[bi].y += v.y; acc[bi].z += v.z; acc[bi].w += v.w;
        }
    }
    __syncthreads();
    if (w == 1) {
        #pragma unroll
        for (int bi = 0; bi < BT; ++bi)
            *(float4*)(red + bi * HIDDEN + lane * 4) = acc[bi];
    }
    __syncthreads();
    if (w == 0) {
        float* slotbase = ws + WS_ACC + (size_t)slot * SLOT_FLOATS;
        #pragma unroll
        for (int bi = 0; bi < BT; ++bi) {
            float4 v = *(const float4*)(red + bi * HIDDEN + lane * 4);
            float4 r = make_float4(acc[bi].x + v.x, acc[bi].y + v.y,
                                   acc[bi].z + v.z, acc[bi].w + v.w);
            float* dst = slotbase + (size_t)(b0 + bi) * HIDDEN + lane * 4;
            if (use_store) {
                *(float4*)dst = r;
            } else {
                atomicAdd(dst + 0, r.x);
                atomicAdd(dst + 1, r.y);
                atomicAdd(dst + 2, r.z);
                atomicAdd(dst + 3, r.w);
            }
        }
    }
}

// ---------------------------------------------------------------- kernel 3
// 1024 threads: 4 threads per column split the S-slot sum (4x shorter latency
// chain), then 256 threads bitonic-sort descending.
__global__ void __launch_bounds__(1024)
reduce_sort_kernel(const float* __restrict__ ws,
                   float* __restrict__ out, int S) {
    __shared__ float v[HIDDEN];
    __shared__ float pq[3][HIDDEN];
    int b   = blockIdx.x;
    int tid = threadIdx.x;
    int c   = tid & 255;
    int q   = tid >> 8;                // 0..3
    float s = 0.f;
    #pragma unroll 4
    for (int sl = q; sl < S; sl += 4)
        s += ws[WS_ACC + (size_t)sl * SLOT_FLOATS + (size_t)b * HIDDEN + c];
    if (q) pq[q - 1][c] = s;
    __syncthreads();
    if (q == 0) v[c] = (s + pq[0][c]) + (pq[1][c] + pq[2][c]);
    __syncthreads();

    for (int k = 2; k <= HIDDEN; k <<= 1) {
        for (int j = k >> 1; j > 0; j >>= 1) {
            if (tid < 256) {
                int ixj = tid ^ j;
                if (ixj > tid) {
                    float a  = v[tid];
                    float bb = v[ixj];
                    bool up  = (tid & k) == 0;
                    if (up ? (a < bb) : (a > bb)) {
                        v[tid] = bb;
                        v[ixj] = a;
                    }
                }
            }
            __syncthreads();
        }
    }
    if (tid < 256) out[(size_t)b * HIDDEN + tid] = v[tid];
}

// ---------------------------------------------------------------- launcher
extern "C" void kernel_launch(void* const* d_in, const int* in_sizes, int n_in,
                              void* d_out, int out_size, void* d_ws, size_t ws_size,
                              hipStream_t stream) {
    const float* x  = (const float*)d_in[0];   // (64, 8192, 1)
    const float* qw = (const float*)d_in[1];   // (128,1)
    const float* qb = (const float*)d_in[2];   // (128,)
    const float* kw = (const float*)d_in[3];   // (128,1)
    // d_in[4] = k_b (cancels in softmax)
    const float* G  = (const float*)d_in[5];   // (8192, 256)
    float* out = (float*)d_out;
    float* ws  = (float*)d_ws;

    long avail = (long)(ws_size / 4) - WS_ACC;
    int S = (int)(avail / SLOT_FLOATS);
    if (S > CHUNKS) S = CHUNKS;
    if (S < 1) S = 1;
    int use_store = (S == CHUNKS) ? 1 : 0;

    stats_kernel<<<BATCH, 256, 0, stream>>>(x, qw, qb, kw, ws);
    if (!use_store)
        zero_kernel<<<256, 256, 0, stream>>>(ws, S * SLOT_FLOATS);
    contract_kernel<<<dim3(CHUNKS, BGROUPS), 256, 0, stream>>>(x, G, ws, S, use_store);
    reduce_sort_kernel<<<BATCH, 1024, 0, stream>>>(ws, out, S);
}